// Round 1
// baseline (248.331 us; speedup 1.0000x reference)
//
#include <hip/hip_runtime.h>
#include <stdint.h>

#define NS   512      // batch size
#define DDIM 256      // feature dim
#define LL   8000     // labels
#define CC   8        // cameras
#define PP   64000    // proxies = LL*CC
#define KTOP 50
#define CAP  1024     // candidate buffer capacity

typedef float f32x4 __attribute__((ext_vector_type(4)));
typedef short bf16x8 __attribute__((ext_vector_type(8)));
typedef short short8 __attribute__((ext_vector_type(8)));

__device__ __forceinline__ ushort f2bf(float x) {
    uint32_t b = __float_as_uint(x);
    b += 0x7fffu + ((b >> 16) & 1u);   // round-to-nearest-even
    return (ushort)(b >> 16);
}
__device__ __forceinline__ float bf2f(ushort u) {
    return __uint_as_float(((uint32_t)u) << 16);
}

// ---------------------------------------------------------------------------
// Kernel 1: normalize feats rows -> bf16; gather labels/cams per sample.
// grid 512 x 64 threads (1 wave per row)
__global__ void k_norm_gather(const float* __restrict__ feats,
                              const int* __restrict__ indexes,
                              const int* __restrict__ ltab,
                              const int* __restrict__ ctab,
                              ushort* __restrict__ feats_b,
                              int* __restrict__ labels,
                              int* __restrict__ cams) {
    const int n = blockIdx.x;
    const int lane = threadIdx.x;  // 0..63, 64*4 = 256 elems
    f32x4 v = ((const f32x4*)(feats + (size_t)n * DDIM))[lane];
    float ss = v[0]*v[0] + v[1]*v[1] + v[2]*v[2] + v[3]*v[3];
#pragma unroll
    for (int off = 32; off > 0; off >>= 1) ss += __shfl_down(ss, off);
    float tot = __shfl(ss, 0);
    float sc = 1.0f / sqrtf(tot);
    ushort4 o;
    o.x = f2bf(v[0] * sc); o.y = f2bf(v[1] * sc);
    o.z = f2bf(v[2] * sc); o.w = f2bf(v[3] * sc);
    ((ushort4*)(feats_b + (size_t)n * DDIM))[lane] = o;
    if (lane == 0) {
        int idx = indexes[n];
        labels[n] = ltab[idx];
        cams[n] = ctab[idx];
    }
}

// ---------------------------------------------------------------------------
// Kernel 2: centers fp32 -> bf16. 16,384,000 elems, 8 per thread.
__global__ void k_conv_centers(const float* __restrict__ c, ushort* __restrict__ cb) {
    size_t i = (size_t)blockIdx.x * blockDim.x + threadIdx.x;
    size_t base = i * 8;
    f32x4 a = *(const f32x4*)(c + base);
    f32x4 b = *(const f32x4*)(c + base + 4);
    short8 r;
    r[0] = (short)f2bf(a[0]); r[1] = (short)f2bf(a[1]);
    r[2] = (short)f2bf(a[2]); r[3] = (short)f2bf(a[3]);
    r[4] = (short)f2bf(b[0]); r[5] = (short)f2bf(b[1]);
    r[6] = (short)f2bf(b[2]); r[7] = (short)f2bf(b[3]);
    *(short8*)(cb + base) = r;
}

// ---------------------------------------------------------------------------
// Kernel 3: sims[n][p] = feats_n[n][:] . centers[p][:]  (both row-major [*,K])
// bf16 MFMA 16x16x32, no LDS: fragments loaded directly from global (A is
// 256 KB L2-resident; B streamed, 4x reuse across row-blocks via L2/L3).
// Block: 256 thr (4 waves), tile BM=128 rows x BN=128 cols, each wave 128x32.
template<bool F32S>
__global__ void k_gemm(const ushort* __restrict__ A, const ushort* __restrict__ B,
                       void* __restrict__ simsv) {
    const int lane = threadIdx.x & 63;
    const int w    = threadIdx.x >> 6;
    const int lr   = lane & 15;
    const int lk   = lane >> 4;
    const int bRow = blockIdx.y * 128;
    const int cBase = blockIdx.x * 128 + w * 32;

    f32x4 zero = {0.f, 0.f, 0.f, 0.f};
    f32x4 acc[8][2];
#pragma unroll
    for (int m = 0; m < 8; ++m) { acc[m][0] = zero; acc[m][1] = zero; }

#pragma unroll
    for (int kb = 0; kb < 8; ++kb) {
        const int kpos = kb * 32 + lk * 8;
        bf16x8 bfr[2];
#pragma unroll
        for (int nn = 0; nn < 2; ++nn)
            bfr[nn] = *(const bf16x8*)(B + (size_t)(cBase + nn * 16 + lr) * DDIM + kpos);
#pragma unroll
        for (int m = 0; m < 8; ++m) {
            bf16x8 afr = *(const bf16x8*)(A + (size_t)(bRow + m * 16 + lr) * DDIM + kpos);
            acc[m][0] = __builtin_amdgcn_mfma_f32_16x16x32_bf16(afr, bfr[0], acc[m][0], 0, 0, 0);
            acc[m][1] = __builtin_amdgcn_mfma_f32_16x16x32_bf16(afr, bfr[1], acc[m][1], 0, 0, 0);
        }
    }
    // C/D layout: col = lane&15, row = (lane>>4)*4 + reg  [m89/m91 verified]
#pragma unroll
    for (int m = 0; m < 8; ++m) {
#pragma unroll
        for (int nn = 0; nn < 2; ++nn) {
#pragma unroll
            for (int j = 0; j < 4; ++j) {
                int row = bRow + m * 16 + lk * 4 + j;
                int col = cBase + nn * 16 + lr;
                size_t idx = (size_t)row * PP + col;
                if constexpr (F32S) ((float*)simsv)[idx] = acc[m][nn][j];
                else                ((ushort*)simsv)[idx] = f2bf(acc[m][nn][j]);
            }
        }
    }
}

// ---------------------------------------------------------------------------
// Kernel 4: per-sample fused intra-LSE + top-K select + inter loss.
// One block (256 thr) per sample.
template<bool F32S>
__global__ __launch_bounds__(256) void k_persample(const void* __restrict__ simsv,
                                                   const int* __restrict__ labels,
                                                   const int* __restrict__ cams,
                                                   float* __restrict__ li,
                                                   float* __restrict__ le) {
    const int n = blockIdx.x;
    const int tid = threadIdx.x;
    const int label = labels[n];
    const int cam = cams[n];
    const float*  rf = (const float*)simsv + (size_t)n * PP;
    const ushort* rh = (const ushort*)simsv + (size_t)n * PP;

    __shared__ float cand[CAP];
    __shared__ float s_redA[256];
    __shared__ float s_redB[256];
    __shared__ int   s_cnt;
    __shared__ float s_tau, s_sig, s_sum, s_M;
    __shared__ float s_pos[CC];

    auto ld4 = [&](int g) -> f32x4 {
        if constexpr (F32S) {
            return ((const f32x4*)rf)[g];
        } else {
            ushort4 u = ((const ushort4*)rh)[g];
            f32x4 r; r[0] = bf2f(u.x); r[1] = bf2f(u.y); r[2] = bf2f(u.z); r[3] = bf2f(u.w);
            return r;
        }
    };
    auto ld1 = [&](int p) -> float {
        if constexpr (F32S) return rf[p];
        else return bf2f(rh[p]);
    };

    // ---- phase 0: sigma estimate from first 8192 entries (masked) ----
    float lss = 0.0f, lcc = 0.0f;
#pragma unroll
    for (int i = 0; i < 8; ++i) {
        int g = tid + i * 256;
        int p0 = g * 4;
        if ((p0 >> 3) == label) continue;  // skip label row
        f32x4 v = ld4(g);
        lss += v[0]*v[0] + v[1]*v[1] + v[2]*v[2] + v[3]*v[3];
        lcc += 4.0f;
    }
    s_redA[tid] = lss; s_redB[tid] = lcc;
    __syncthreads();
    for (int off = 128; off > 0; off >>= 1) {
        if (tid < off) { s_redA[tid] += s_redA[tid + off]; s_redB[tid] += s_redB[tid + off]; }
        __syncthreads();
    }
    if (tid == 0) {
        float sig = sqrtf(s_redA[0] / fmaxf(s_redB[0], 1.0f));
        s_sig = sig;
        s_tau = 2.9f * sig;  // expect ~120 of 64000 above (normal tail)
    }

    // ---- phase 1: full-row scan: intra online LSE + candidate collect ----
    const float K2 = 28.853900817779268f;  // log2(e)/T
    float my_m = -1e30f, my_s = 0.0f;      // intra running max/sum (log2 domain)
    int pass = 0;
    int c;
    for (;;) {
        __syncthreads();
        if (tid == 0) s_cnt = 0;
        __syncthreads();
        float tau = s_tau;
        for (int g = tid; g < PP / 4; g += 256) {
            int p0 = g * 4;
            f32x4 v = ld4(g);
            if (pass == 0 && ((p0 & 4) == (cam & 4))) {
                // intra-cam entry is element (cam&3) of this float4
                float vi = (cam & 1) ? ((cam & 2) ? v[3] : v[1])
                                     : ((cam & 2) ? v[2] : v[0]);
                float y = vi * K2;
                if (y > my_m) { my_s = my_s * exp2f(my_m - y) + 1.0f; my_m = y; }
                else          { my_s += exp2f(y - my_m); }
            }
            if ((p0 >> 3) != label) {
#pragma unroll
                for (int j = 0; j < 4; ++j) {
                    if (v[j] > tau) {
                        int id = atomicAdd(&s_cnt, 1);
                        if (id < CAP) cand[id] = v[j];
                    }
                }
            }
        }
        __syncthreads();
        c = s_cnt;
        if ((c >= KTOP && c <= CAP) || pass >= 24) break;
        if (tid == 0) s_tau = (c < KTOP) ? (tau - 0.25f * s_sig) : (tau + 0.125f * s_sig);
        pass++;
    }
    if (c > CAP) c = CAP;

    // ---- intra block-reduce of (m,s) pairs ----
    s_redA[tid] = my_m; s_redB[tid] = my_s;
    __syncthreads();
    for (int off = 128; off > 0; off >>= 1) {
        if (tid < off) {
            float m1 = s_redA[tid],       s1 = s_redB[tid];
            float m2 = s_redA[tid + off], s2 = s_redB[tid + off];
            float M = fmaxf(m1, m2);
            s_redB[tid] = s1 * exp2f(m1 - M) + s2 * exp2f(m2 - M);
            s_redA[tid] = M;
        }
        __syncthreads();
    }
    if (tid == 0) {
        float lse_nat = 0.6931471805599453f * (s_redA[0] + log2f(s_redB[0]));
        float xl = ld1(label * CC + cam) * 20.0f;  // 1/T = 20
        li[n] = lse_nat - xl;
    }
    if (tid < CC) s_pos[tid] = ld1(label * CC + tid);
    __syncthreads();

    // ---- inter: max over candidates + positives ----
    float lm = -1e30f;
    for (int i = tid; i < c; i += 256) lm = fmaxf(lm, cand[i]);
    if (tid < CC) lm = fmaxf(lm, s_pos[tid]);
    s_redA[tid] = lm;
    __syncthreads();
    for (int off = 128; off > 0; off >>= 1) {
        if (tid < off) s_redA[tid] = fmaxf(s_redA[tid], s_redA[tid + off]);
        __syncthreads();
    }
    if (tid == 0) { s_M = s_redA[0]; s_sum = 0.0f; }
    __syncthreads();
    const float M = s_M;

    // exact top-K among candidates via rank counting (ties broken by index)
    for (int i = tid; i < c; i += 256) {
        float v = cand[i];
        int r = 0;
        for (int j = 0; j < c; ++j) {
            float u = cand[j];
            r += (u > v) || (u == v && j < i);
        }
        if (r < KTOP) atomicAdd(&s_sum, exp2f((v - M) * K2));
    }
    if (tid < CC) atomicAdd(&s_sum, exp2f((s_pos[tid] - M) * K2));
    __syncthreads();
    if (tid == 0) {
        float possum = 0.0f;
#pragma unroll
        for (int j = 0; j < CC; ++j) possum += s_pos[j];
        float lse_nat = M * 20.0f + logf(s_sum);
        le[n] = lse_nat - possum * 20.0f / 8.0f;
    }
}

// ---------------------------------------------------------------------------
// Kernel 5: per-camera segment means -> 2 outputs.
__global__ void k_finalize(const float* __restrict__ li, const float* __restrict__ le,
                           const int* __restrict__ cams, float* __restrict__ out) {
    __shared__ float si[CC], se[CC];
    __shared__ int sc[CC];
    int tid = threadIdx.x;
    if (tid < CC) { si[tid] = 0.f; se[tid] = 0.f; sc[tid] = 0; }
    __syncthreads();
    for (int i = tid; i < NS; i += 256) {
        int cm = cams[i];
        atomicAdd(&si[cm], li[i]);
        atomicAdd(&se[cm], le[i]);
        atomicAdd(&sc[cm], 1);
    }
    __syncthreads();
    if (tid == 0) {
        float a = 0.f, b = 0.f;
        for (int cm = 0; cm < CC; ++cm) {
            if (sc[cm] > 0) {
                a += si[cm] / (float)sc[cm];
                b += se[cm] / (float)sc[cm];
            }
        }
        out[0] = a;
        out[1] = 0.5f * b;
    }
}

// ---------------------------------------------------------------------------
extern "C" void kernel_launch(void* const* d_in, const int* in_sizes, int n_in,
                              void* d_out, int out_size, void* d_ws, size_t ws_size,
                              hipStream_t stream) {
    const float* feats   = (const float*)d_in[0];
    const int*   indexes = (const int*)d_in[1];
    const int*   ltab    = (const int*)d_in[2];
    const int*   ctab    = (const int*)d_in[3];
    const float* centers = (const float*)d_in[4];
    float* out = (float*)d_out;

    const size_t SZ_SIMS_F32 = (size_t)NS * PP * sizeof(float);   // 131 MB
    const size_t SZ_SIMS_BF  = (size_t)NS * PP * sizeof(ushort);  // 65.5 MB
    const size_t SZ_CB = (size_t)PP * DDIM * sizeof(ushort);      // 32.8 MB
    const size_t SZ_FB = (size_t)NS * DDIM * sizeof(ushort);      // 256 KB
    const size_t SMALL = 16 * 1024;

    const bool f32s = ws_size >= (SZ_SIMS_F32 + SZ_CB + SZ_FB + SMALL);

    char* p = (char*)d_ws;
    void* sims = (void*)p;       p += f32s ? SZ_SIMS_F32 : SZ_SIMS_BF;
    ushort* cb = (ushort*)p;     p += SZ_CB;
    ushort* fb = (ushort*)p;     p += SZ_FB;
    int* labels = (int*)p;       p += 2048;
    int* cams   = (int*)p;       p += 2048;
    float* li   = (float*)p;     p += 2048;
    float* le   = (float*)p;     p += 2048;

    hipLaunchKernelGGL(k_norm_gather, dim3(NS), dim3(64), 0, stream,
                       feats, indexes, ltab, ctab, fb, labels, cams);
    hipLaunchKernelGGL(k_conv_centers, dim3(8000), dim3(256), 0, stream, centers, cb);
    if (f32s) {
        hipLaunchKernelGGL((k_gemm<true>), dim3(500, 4), dim3(256), 0, stream, fb, cb, sims);
        hipLaunchKernelGGL((k_persample<true>), dim3(NS), dim3(256), 0, stream,
                           sims, labels, cams, li, le);
    } else {
        hipLaunchKernelGGL((k_gemm<false>), dim3(500, 4), dim3(256), 0, stream, fb, cb, sims);
        hipLaunchKernelGGL((k_persample<false>), dim3(NS), dim3(256), 0, stream,
                           sims, labels, cams, li, le);
    }
    hipLaunchKernelGGL(k_finalize, dim3(1), dim3(256), 0, stream, li, le, cams, out);
}

// Round 6
// 245.952 us; speedup vs baseline: 1.0097x; 1.0097x over previous
//
#include <hip/hip_runtime.h>
#include <stdint.h>

#define NS   512      // batch size
#define DDIM 256      // feature dim
#define LL   8000     // labels
#define CC   8        // cameras
#define PP   64000    // proxies = LL*CC
#define KTOP 50
#define CAP  1024     // candidate buffer capacity

typedef float f32x4 __attribute__((ext_vector_type(4)));
typedef short bf16x8 __attribute__((ext_vector_type(8)));
typedef short short8 __attribute__((ext_vector_type(8)));

__device__ __forceinline__ ushort f2bf(float x) {
    uint32_t b = __float_as_uint(x);
    b += 0x7fffu + ((b >> 16) & 1u);   // round-to-nearest-even
    return (ushort)(b >> 16);
}
__device__ __forceinline__ float bf2f(ushort u) {
    return __uint_as_float(((uint32_t)u) << 16);
}

// ---------------------------------------------------------------------------
// Kernel 1: normalize feats rows -> bf16; gather labels/cams per sample.
__global__ void k_norm_gather(const float* __restrict__ feats,
                              const int* __restrict__ indexes,
                              const int* __restrict__ ltab,
                              const int* __restrict__ ctab,
                              ushort* __restrict__ feats_b,
                              int* __restrict__ labels,
                              int* __restrict__ cams) {
    const int n = blockIdx.x;
    const int lane = threadIdx.x;  // 0..63, 64*4 = 256 elems
    f32x4 v = ((const f32x4*)(feats + (size_t)n * DDIM))[lane];
    float ss = v[0]*v[0] + v[1]*v[1] + v[2]*v[2] + v[3]*v[3];
#pragma unroll
    for (int off = 32; off > 0; off >>= 1) ss += __shfl_down(ss, off);
    float tot = __shfl(ss, 0);
    float sc = 1.0f / sqrtf(tot);
    ushort4 o;
    o.x = f2bf(v[0] * sc); o.y = f2bf(v[1] * sc);
    o.z = f2bf(v[2] * sc); o.w = f2bf(v[3] * sc);
    ((ushort4*)(feats_b + (size_t)n * DDIM))[lane] = o;
    if (lane == 0) {
        int idx = indexes[n];
        labels[n] = ltab[idx];
        cams[n] = ctab[idx];
    }
}

// ---------------------------------------------------------------------------
// Kernel 2: GEMM with inline f32->bf16 conversion of B (centers), B panel
// held entirely in registers per wave (16 frags = 64 VGPRs), A streamed from
// L2 (256 KB total). Writes: bf16 sims (bulk), f32 positives (label row),
// f32 intra-cam slice (exact terms that enter the loss linearly).
// grid (500, 4), 256 thr = 4 waves; wave tile 128 rows x 32 cols.
__global__ __launch_bounds__(256, 2)
void k_gemm(const ushort* __restrict__ A, const float* __restrict__ B,
            const int* __restrict__ labels, const int* __restrict__ cams,
            ushort* __restrict__ sims, float* __restrict__ intrabuf,
            float* __restrict__ posbuf) {
    const int lane = threadIdx.x & 63;
    const int w    = threadIdx.x >> 6;
    const int lr   = lane & 15;
    const int lk   = lane >> 4;
    const int bRow = blockIdx.y * 128;
    const int cBase = blockIdx.x * 128 + w * 32;

    __shared__ int s_lab[128], s_cam[128];
    if (threadIdx.x < 128) {
        s_lab[threadIdx.x] = labels[bRow + threadIdx.x];
        s_cam[threadIdx.x] = cams[bRow + threadIdx.x];
    }

    // ---- load + convert full B panel for this wave: 16 frags, 32 x 16B loads
    bf16x8 bfr[2][8];
#pragma unroll
    for (int nn = 0; nn < 2; ++nn) {
#pragma unroll
        for (int kb = 0; kb < 8; ++kb) {
            const float* src = B + (size_t)(cBase + nn * 16 + lr) * DDIM + kb * 32 + lk * 8;
            f32x4 a = *(const f32x4*)src;
            f32x4 b = *(const f32x4*)(src + 4);
            bf16x8 r;
            r[0] = (short)f2bf(a[0]); r[1] = (short)f2bf(a[1]);
            r[2] = (short)f2bf(a[2]); r[3] = (short)f2bf(a[3]);
            r[4] = (short)f2bf(b[0]); r[5] = (short)f2bf(b[1]);
            r[6] = (short)f2bf(b[2]); r[7] = (short)f2bf(b[3]);
            bfr[nn][kb] = r;
        }
    }
    __syncthreads();   // s_lab/s_cam visible before epilogue

    f32x4 zero = {0.f, 0.f, 0.f, 0.f};
    f32x4 acc[8][2];
#pragma unroll
    for (int m = 0; m < 8; ++m) { acc[m][0] = zero; acc[m][1] = zero; }

#pragma unroll
    for (int kb = 0; kb < 8; ++kb) {
        const int kpos = kb * 32 + lk * 8;
#pragma unroll
        for (int m = 0; m < 8; ++m) {
            bf16x8 afr = *(const bf16x8*)(A + (size_t)(bRow + m * 16 + lr) * DDIM + kpos);
            acc[m][0] = __builtin_amdgcn_mfma_f32_16x16x32_bf16(afr, bfr[0][kb], acc[m][0], 0, 0, 0);
            acc[m][1] = __builtin_amdgcn_mfma_f32_16x16x32_bf16(afr, bfr[1][kb], acc[m][1], 0, 0, 0);
        }
    }

    // C/D layout: col = lane&15, row = (lane>>4)*4 + reg  [m89/m91 verified]
#pragma unroll
    for (int m = 0; m < 8; ++m) {
#pragma unroll
        for (int nn = 0; nn < 2; ++nn) {
#pragma unroll
            for (int j = 0; j < 4; ++j) {
                int rl  = m * 16 + lk * 4 + j;
                int row = bRow + rl;
                int col = cBase + nn * 16 + lr;
                float v = acc[m][nn][j];
                sims[(size_t)row * PP + col] = f2bf(v);
                int g = col >> 3, cc = col & 7;
                if (g == s_lab[rl]) posbuf[row * CC + cc] = v;
                if (cc == s_cam[rl]) intrabuf[(size_t)row * LL + g] = v;
            }
        }
    }
}

// ---------------------------------------------------------------------------
// Kernel 3: per-sample fused intra-LSE (f32 slice) + top-K select (bf16 sims)
// + inter loss (f32 positives). One block (256 thr) per sample.
__global__ __launch_bounds__(256)
void k_persample(const ushort* __restrict__ sims, const float* __restrict__ intrabuf,
                 const float* __restrict__ posbuf, const int* __restrict__ labels,
                 const int* __restrict__ cams, float* __restrict__ li,
                 float* __restrict__ le) {
    const int n = blockIdx.x;
    const int tid = threadIdx.x;
    const int label = labels[n];
    const int cam = cams[n];
    const ushort* row = sims + (size_t)n * PP;
    const float* irow = intrabuf + (size_t)n * LL;

    __shared__ float cand[CAP];
    __shared__ float s_redA[256];
    __shared__ float s_redB[256];
    __shared__ int   s_cnt;
    __shared__ float s_tau, s_sig, s_sum, s_M;
    __shared__ float s_pos[CC];

    const float K2 = 28.853900817779268f;  // log2(e)/T

    // ---- phase 0: intra scan over exact f32 slice: sigma + online LSE ----
    float lss = 0.0f, lcc = 0.0f;
    float my_m = -1e30f, my_s = 0.0f;
    for (int g = tid; g < LL / 4; g += 256) {
        f32x4 v = ((const f32x4*)irow)[g];
#pragma unroll
        for (int j = 0; j < 4; ++j) {
            int l = g * 4 + j;
            float y = v[j] * K2;
            if (y > my_m) { my_s = my_s * exp2f(my_m - y) + 1.0f; my_m = y; }
            else          { my_s += exp2f(y - my_m); }
            if (l != label) { lss += v[j] * v[j]; lcc += 1.0f; }
        }
    }
    s_redA[tid] = lss; s_redB[tid] = lcc;
    __syncthreads();
    for (int off = 128; off > 0; off >>= 1) {
        if (tid < off) { s_redA[tid] += s_redA[tid + off]; s_redB[tid] += s_redB[tid + off]; }
        __syncthreads();
    }
    if (tid == 0) {
        float sig = sqrtf(s_redA[0] / fmaxf(s_redB[0], 1.0f));
        s_sig = sig;
        s_tau = 2.9f * sig;  // expect ~120 of 64000 above (normal tail)
    }
    __syncthreads();
    s_redA[tid] = my_m; s_redB[tid] = my_s;
    __syncthreads();
    for (int off = 128; off > 0; off >>= 1) {
        if (tid < off) {
            float m1 = s_redA[tid],       s1 = s_redB[tid];
            float m2 = s_redA[tid + off], s2 = s_redB[tid + off];
            float M = fmaxf(m1, m2);
            s_redB[tid] = s1 * exp2f(m1 - M) + s2 * exp2f(m2 - M);
            s_redA[tid] = M;
        }
        __syncthreads();
    }
    if (tid == 0) {
        float lse_nat = 0.6931471805599453f * (s_redA[0] + log2f(s_redB[0]));
        li[n] = lse_nat - posbuf[n * CC + cam] * 20.0f;  // exact f32 logit
    }
    if (tid < CC) s_pos[tid] = posbuf[n * CC + tid];

    // ---- phase 1: candidate collect over bf16 sims (retry threshold) ----
    int pass = 0;
    int c;
    for (;;) {
        __syncthreads();
        if (tid == 0) s_cnt = 0;
        __syncthreads();
        float tau = s_tau;
        for (int g = tid; g < LL; g += 256) {       // one ushort8 = one label group
            if (g == label) continue;
            short8 u = ((const short8*)row)[g];
#pragma unroll
            for (int j = 0; j < 8; ++j) {
                float v = bf2f((ushort)u[j]);
                if (v > tau) {
                    int id = atomicAdd(&s_cnt, 1);
                    if (id < CAP) cand[id] = v;
                }
            }
        }
        __syncthreads();
        c = s_cnt;
        if ((c >= KTOP && c <= CAP) || pass >= 24) break;
        if (tid == 0) s_tau = (c < KTOP) ? (tau - 0.25f * s_sig) : (tau + 0.125f * s_sig);
        pass++;
    }
    if (c > CAP) c = CAP;

    // ---- phase 2: max over candidates + positives ----
    float lm = -1e30f;
    for (int i = tid; i < c; i += 256) lm = fmaxf(lm, cand[i]);
    if (tid < CC) lm = fmaxf(lm, s_pos[tid]);
    s_redA[tid] = lm;
    __syncthreads();
    for (int off = 128; off > 0; off >>= 1) {
        if (tid < off) s_redA[tid] = fmaxf(s_redA[tid], s_redA[tid + off]);
        __syncthreads();
    }
    if (tid == 0) { s_M = s_redA[0]; s_sum = 0.0f; }
    __syncthreads();
    const float M = s_M;

    // exact top-K among candidates via rank counting (ties broken by index)
    for (int i = tid; i < c; i += 256) {
        float v = cand[i];
        int r = 0;
        for (int j = 0; j < c; ++j) {
            float u = cand[j];
            r += (u > v) || (u == v && j < i);
        }
        if (r < KTOP) atomicAdd(&s_sum, exp2f((v - M) * K2));
    }
    if (tid < CC) atomicAdd(&s_sum, exp2f((s_pos[tid] - M) * K2));
    __syncthreads();
    if (tid == 0) {
        float possum = 0.0f;
#pragma unroll
        for (int j = 0; j < CC; ++j) possum += s_pos[j];
        float lse_nat = M * 20.0f + logf(s_sum);
        le[n] = lse_nat - possum * 20.0f / 8.0f;
    }
}

// ---------------------------------------------------------------------------
// Kernel 4: per-camera segment means -> 2 outputs.
__global__ void k_finalize(const float* __restrict__ li, const float* __restrict__ le,
                           const int* __restrict__ cams, float* __restrict__ out) {
    __shared__ float si[CC], se[CC];
    __shared__ int sc[CC];
    int tid = threadIdx.x;
    if (tid < CC) { si[tid] = 0.f; se[tid] = 0.f; sc[tid] = 0; }
    __syncthreads();
    for (int i = tid; i < NS; i += 256) {
        int cm = cams[i];
        atomicAdd(&si[cm], li[i]);
        atomicAdd(&se[cm], le[i]);
        atomicAdd(&sc[cm], 1);
    }
    __syncthreads();
    if (tid == 0) {
        float a = 0.f, b = 0.f;
        for (int cm = 0; cm < CC; ++cm) {
            if (sc[cm] > 0) {
                a += si[cm] / (float)sc[cm];
                b += se[cm] / (float)sc[cm];
            }
        }
        out[0] = a;
        out[1] = 0.5f * b;
    }
}

// ---------------------------------------------------------------------------
extern "C" void kernel_launch(void* const* d_in, const int* in_sizes, int n_in,
                              void* d_out, int out_size, void* d_ws, size_t ws_size,
                              hipStream_t stream) {
    const float* feats   = (const float*)d_in[0];
    const int*   indexes = (const int*)d_in[1];
    const int*   ltab    = (const int*)d_in[2];
    const int*   ctab    = (const int*)d_in[3];
    const float* centers = (const float*)d_in[4];
    float* out = (float*)d_out;

    const size_t SZ_SIMS  = (size_t)NS * PP * sizeof(ushort);   // 65.5 MB
    const size_t SZ_INTRA = (size_t)NS * LL * sizeof(float);    // 16.4 MB
    const size_t SZ_POS   = (size_t)NS * CC * sizeof(float);    // 16 KB
    const size_t SZ_FB    = (size_t)NS * DDIM * sizeof(ushort); // 256 KB

    char* p = (char*)d_ws;
    ushort* sims    = (ushort*)p;  p += SZ_SIMS;
    float*  intrabf = (float*)p;   p += SZ_INTRA;
    float*  posbuf  = (float*)p;   p += SZ_POS;
    ushort* fb      = (ushort*)p;  p += SZ_FB;
    int* labels = (int*)p;         p += 2048;
    int* cams   = (int*)p;         p += 2048;
    float* li   = (float*)p;       p += 2048;
    float* le   = (float*)p;       p += 2048;

    hipLaunchKernelGGL(k_norm_gather, dim3(NS), dim3(64), 0, stream,
                       feats, indexes, ltab, ctab, fb, labels, cams);
    hipLaunchKernelGGL(k_gemm, dim3(500, 4), dim3(256), 0, stream,
                       fb, centers, labels, cams, sims, intrabf, posbuf);
    hipLaunchKernelGGL(k_persample, dim3(NS), dim3(256), 0, stream,
                       sims, intrabf, posbuf, labels, cams, li, le);
    hipLaunchKernelGGL(k_finalize, dim3(1), dim3(256), 0, stream, li, le, cams, out);
}

// Round 8
// 235.509 us; speedup vs baseline: 1.0544x; 1.0443x over previous
//
#include <hip/hip_runtime.h>
#include <stdint.h>

#define NS   512      // batch size
#define DDIM 256      // feature dim
#define LL   8000     // labels
#define CC   8        // cameras
#define PP   64000    // proxies = LL*C
#define KTOP 50
#define CAP  1024     // candidate buffer capacity per row
#define NBLK 2000     // PP / 32 cols per block
#define K2C  28.853900817779268f   // log2(e)/T, T=0.05

typedef float f32x4 __attribute__((ext_vector_type(4)));
typedef short bf16x8 __attribute__((ext_vector_type(8)));

__device__ __forceinline__ ushort f2bf(float x) {
    uint32_t b = __float_as_uint(x);
    b += 0x7fffu + ((b >> 16) & 1u);   // round-to-nearest-even
    return (ushort)(b >> 16);
}
__device__ __forceinline__ float bf2f(ushort u) {
    return __uint_as_float(((uint32_t)u) << 16);
}

// ---------------------------------------------------------------------------
// Kernel 1: normalize feats rows -> bf16; gather labels/cams per sample.
__global__ void k_norm_gather(const float* __restrict__ feats,
                              const int* __restrict__ indexes,
                              const int* __restrict__ ltab,
                              const int* __restrict__ ctab,
                              ushort* __restrict__ feats_b,
                              int* __restrict__ labels,
                              int* __restrict__ cams) {
    const int n = blockIdx.x;
    const int lane = threadIdx.x;  // 0..63
    f32x4 v = ((const f32x4*)(feats + (size_t)n * DDIM))[lane];
    float ss = v[0]*v[0] + v[1]*v[1] + v[2]*v[2] + v[3]*v[3];
#pragma unroll
    for (int off = 32; off > 0; off >>= 1) ss += __shfl_down(ss, off);
    float tot = __shfl(ss, 0);
    float sc = 1.0f / sqrtf(tot);
    ushort4 o;
    o.x = f2bf(v[0] * sc); o.y = f2bf(v[1] * sc);
    o.z = f2bf(v[2] * sc); o.w = f2bf(v[3] * sc);
    ((ushort4*)(feats_b + (size_t)n * DDIM))[lane] = o;
    if (lane == 0) {
        int idx = indexes[n];
        labels[n] = ltab[idx];
        cams[n] = ctab[idx];
    }
}

// ---------------------------------------------------------------------------
// Kernel 2: sigma estimate. 64 blocks, each samples one proxy column and dots
// it against all 512 rows; accumulates sum of v^2 into sig_acc[0].
__global__ __launch_bounds__(256) void k_sigma(const ushort* __restrict__ fb,
                                               const float* __restrict__ B,
                                               float* __restrict__ sig_acc) {
    __shared__ float cf[DDIM];
    __shared__ float red[256];
    const int tid = threadIdx.x;
    const int p = blockIdx.x * 997 + 123;          // 64 spread columns, < 64000
    cf[tid] = bf2f(f2bf(B[(size_t)p * DDIM + tid]));
    __syncthreads();
    float s = 0.0f;
#pragma unroll
    for (int rr = 0; rr < 2; ++rr) {
        int r = tid * 2 + rr;
        const ushort* a = fb + (size_t)r * DDIM;
        float d = 0.0f;
        for (int k = 0; k < DDIM; k += 8) {
            bf16x8 av = *(const bf16x8*)(a + k);
#pragma unroll
            for (int j = 0; j < 8; ++j) d += bf2f((ushort)av[j]) * cf[k + j];
        }
        s += d * d;
    }
    red[tid] = s;
    __syncthreads();
    for (int off = 128; off > 0; off >>= 1) {
        if (tid < off) red[tid] += red[tid + off];
        __syncthreads();
    }
    if (tid == 0) atomicAdd(sig_acc, red[0]);
}

// ---------------------------------------------------------------------------
// Kernel 3: fused GEMM + loss-statistics epilogue. NO sims materialization.
// Block b: all 512 rows x 32 cols [b*32, b*32+32) (= 4 label groups).
// B panel staged in LDS (bf16, padded); A streamed from L2.
// Emits: partial[b][r] = sum exp2(K2*v) over this block's 4 own-cam cols;
//        posbuf[r][0..8) when block holds r's label group;
//        cand[r][*] append (global atomic) for v > tau outside label group.
__global__ __launch_bounds__(256, 4)
void k_gemm_fused(const ushort* __restrict__ A, const float* __restrict__ B,
                  const int* __restrict__ labels, const int* __restrict__ cams,
                  const float* __restrict__ sig_acc,
                  float* __restrict__ partial, float* __restrict__ cand,
                  int* __restrict__ gcount, float* __restrict__ posbuf) {
    const int bx   = blockIdx.x;           // 0..1999
    const int cBase = bx * 32;
    const int tid  = threadIdx.x;
    const int lane = tid & 63;
    const int w    = tid >> 6;             // wave id: rows [w*128, w*128+128)
    const int lr   = lane & 15;
    const int lk   = lane >> 4;

    __shared__ ushort sB[32][264];         // [col][k], pad 256->264 (bank-safe)
    __shared__ int   s_lab[NS];
    __shared__ int   s_cam[NS];
    __shared__ float s_intra[NS];

    // ---- stage B panel: 32 cols x 256 k, f32 -> bf16 ----
#pragma unroll
    for (int it = 0; it < 8; ++it) {
        int q   = tid + it * 256;          // f32x4 chunk id, 0..2047
        int col = q >> 6;                  // 0..31
        int k4  = q & 63;                  // f32x4 within col
        f32x4 a = *(const f32x4*)(B + (size_t)(cBase + col) * DDIM + k4 * 4);
        ushort4 o;
        o.x = f2bf(a[0]); o.y = f2bf(a[1]); o.z = f2bf(a[2]); o.w = f2bf(a[3]);
        *(ushort4*)(&sB[col][k4 * 4]) = o;
    }
    for (int r = tid; r < NS; r += 256) {
        s_lab[r] = labels[r];
        s_cam[r] = cams[r];
        s_intra[r] = 0.0f;
    }
    __syncthreads();

    const float tau = 2.9f * sqrtf(sig_acc[0] * (1.0f / 32768.0f));

    // ---- MFMA main loop: 512 rows x 32 cols x K=256 ----
    f32x4 zero = {0.f, 0.f, 0.f, 0.f};
    f32x4 acc[8][2];
#pragma unroll
    for (int m = 0; m < 8; ++m) { acc[m][0] = zero; acc[m][1] = zero; }

#pragma unroll
    for (int kb = 0; kb < 8; ++kb) {
        const int kpos = kb * 32 + lk * 8;
        bf16x8 b0 = *(const bf16x8*)(&sB[lr][kpos]);
        bf16x8 b1 = *(const bf16x8*)(&sB[16 + lr][kpos]);
#pragma unroll
        for (int m = 0; m < 8; ++m) {
            bf16x8 a = *(const bf16x8*)(A + (size_t)(w * 128 + m * 16 + lr) * DDIM + kpos);
            acc[m][0] = __builtin_amdgcn_mfma_f32_16x16x32_bf16(a, b0, acc[m][0], 0, 0, 0);
            acc[m][1] = __builtin_amdgcn_mfma_f32_16x16x32_bf16(a, b1, acc[m][1], 0, 0, 0);
        }
    }

    // ---- epilogue: C/D layout col = lane&15 (+16nn), row = lk*4 + j (+16m) ----
#pragma unroll
    for (int m = 0; m < 8; ++m) {
#pragma unroll
        for (int j = 0; j < 4; ++j) {
            const int r   = w * 128 + m * 16 + lk * 4 + j;
            const int lab = s_lab[r];
            const int cm  = s_cam[r];
#pragma unroll
            for (int nn = 0; nn < 2; ++nn) {
                const int c_loc = nn * 16 + lr;
                const float v = acc[m][nn][j];
                if ((c_loc & 7) == cm)
                    atomicAdd(&s_intra[r], exp2f(v * K2C));
                const int g = (cBase + c_loc) >> 3;
                if (g == lab) {
                    posbuf[r * CC + (c_loc & 7)] = v;
                } else if (v > tau) {
                    int id = atomicAdd(&gcount[r], 1);
                    if (id < CAP) cand[(size_t)r * CAP + id] = v;
                }
            }
        }
    }
    __syncthreads();
    for (int r = tid; r < NS; r += 256)
        partial[(size_t)bx * NS + r] = s_intra[r];
}

// ---------------------------------------------------------------------------
// Kernel 4: fixup (correctness backstop; uniform early-exit in practice).
// If a row's candidate count is out of [KTOP, CAP], bisect tau on a full
// recompute of that row and re-collect.
__global__ __launch_bounds__(256) void k_fixup(const ushort* __restrict__ fb,
                                               const float* __restrict__ B,
                                               const int* __restrict__ labels,
                                               float* __restrict__ cand,
                                               int* __restrict__ gcount) {
    const int n = blockIdx.x;
    const int c0 = gcount[n];
    if (c0 >= KTOP && c0 <= CAP) return;   // uniform exit — the normal path

    const int tid = threadIdx.x;
    __shared__ float f[DDIM];
    __shared__ float s_lo, s_hi;
    __shared__ int   red[256];
    __shared__ int   s_done;
    __shared__ int   s_cnt;
    if (tid < DDIM) f[tid] = bf2f(fb[(size_t)n * DDIM + tid]);
    const int label = labels[n];
    if (tid == 0) { s_lo = -1.01f; s_hi = 1.01f; s_done = 0; }
    __syncthreads();

    for (int it = 0; it < 16 && !s_done; ++it) {
        float tm = 0.5f * (s_lo + s_hi);
        int cnt = 0;
        for (int p = tid; p < PP; p += 256) {
            if ((p >> 3) == label) continue;
            const float* col = B + (size_t)p * DDIM;
            float d = 0.0f;
            for (int k = 0; k < DDIM; ++k) d += f[k] * bf2f(f2bf(col[k]));
            cnt += (d > tm);
        }
        red[tid] = cnt;
        __syncthreads();
        for (int off = 128; off > 0; off >>= 1) {
            if (tid < off) red[tid] += red[tid + off];
            __syncthreads();
        }
        int tot = red[0];
        __syncthreads();
        if (tot >= KTOP && tot <= CAP) {
            // collect at tm
            if (tid == 0) s_cnt = 0;
            __syncthreads();
            for (int p = tid; p < PP; p += 256) {
                if ((p >> 3) == label) continue;
                const float* col = B + (size_t)p * DDIM;
                float d = 0.0f;
                for (int k = 0; k < DDIM; ++k) d += f[k] * bf2f(f2bf(col[k]));
                if (d > tm) {
                    int id = atomicAdd(&s_cnt, 1);
                    if (id < CAP) cand[(size_t)n * CAP + id] = d;
                }
            }
            __syncthreads();
            if (tid == 0) { gcount[n] = (s_cnt > CAP) ? CAP : s_cnt; s_done = 1; }
            __syncthreads();
        } else {
            if (tid == 0) { if (tot < KTOP) s_hi = tm; else s_lo = tm; }
            __syncthreads();
        }
    }
    if (s_done) return;
    // last resort: collect at s_lo (count >= KTOP side), truncated at CAP
    if (tid == 0) s_cnt = 0;
    __syncthreads();
    float tl = s_lo;
    for (int p = tid; p < PP; p += 256) {
        if ((p >> 3) == label) continue;
        const float* col = B + (size_t)p * DDIM;
        float d = 0.0f;
        for (int k = 0; k < DDIM; ++k) d += f[k] * bf2f(f2bf(col[k]));
        if (d > tl) {
            int id = atomicAdd(&s_cnt, 1);
            if (id < CAP) cand[(size_t)n * CAP + id] = d;
        }
    }
    __syncthreads();
    if (tid == 0) gcount[n] = (s_cnt > CAP) ? CAP : s_cnt;
}

// ---------------------------------------------------------------------------
// Kernel 5: per-row losses. Reduce intra partials; exact top-K among
// candidates by rank counting; both LSEs without max-subtraction (|sim|<=1
// => terms in [2^-29, 2^29], f32-safe).
__global__ __launch_bounds__(256) void k_row(const float* __restrict__ partial,
                                             const float* __restrict__ cand,
                                             const int* __restrict__ gcount,
                                             const float* __restrict__ posbuf,
                                             const int* __restrict__ labels,
                                             const int* __restrict__ cams,
                                             float* __restrict__ li,
                                             float* __restrict__ le) {
    const int n = blockIdx.x;
    const int tid = threadIdx.x;
    __shared__ float red[256];
    __shared__ float spos[CC];
    __shared__ float scand[CAP];

    // ---- intra: sum 2000 partials ----
    float s = 0.0f;
    for (int b = tid; b < NBLK; b += 256) s += partial[(size_t)b * NS + n];
    red[tid] = s;
    __syncthreads();
    for (int off = 128; off > 0; off >>= 1) {
        if (tid < off) red[tid] += red[tid + off];
        __syncthreads();
    }
    if (tid < CC) spos[tid] = posbuf[n * CC + tid];
    __syncthreads();
    if (tid == 0) li[n] = logf(red[0]) * 0.6931471805599453f / 0.6931471805599453f - 20.0f * spos[cams[n]];
    __syncthreads();

    // ---- inter: top-K rank count + positives ----
    int c = gcount[n];
    if (c > CAP) c = CAP;
    for (int i = tid; i < c; i += 256) scand[i] = cand[(size_t)n * CAP + i];
    __syncthreads();
    float sum = 0.0f;
    for (int i = tid; i < c; i += 256) {
        float v = scand[i];
        int rk = 0;
        for (int j = 0; j < c; ++j) {
            float u = scand[j];
            rk += (u > v) || (u == v && j < i);
        }
        if (rk < KTOP) sum += exp2f(v * K2C);
    }
    if (tid < CC) sum += exp2f(spos[tid] * K2C);
    red[tid] = sum;
    __syncthreads();
    for (int off = 128; off > 0; off >>= 1) {
        if (tid < off) red[tid] += red[tid + off];
        __syncthreads();
    }
    if (tid == 0) {
        float ps = 0.0f;
#pragma unroll
        for (int j = 0; j < CC; ++j) ps += spos[j];
        le[n] = logf(red[0]) - 2.5f * ps;   // 20/8 = 2.5
    }
}

// ---------------------------------------------------------------------------
// Kernel 6: per-camera segment means -> 2 outputs.
__global__ void k_finalize(const float* __restrict__ li, const float* __restrict__ le,
                           const int* __restrict__ cams, float* __restrict__ out) {
    __shared__ float si[CC], se[CC];
    __shared__ int sc[CC];
    int tid = threadIdx.x;
    if (tid < CC) { si[tid] = 0.f; se[tid] = 0.f; sc[tid] = 0; }
    __syncthreads();
    for (int i = tid; i < NS; i += 256) {
        int cm = cams[i];
        atomicAdd(&si[cm], li[i]);
        atomicAdd(&se[cm], le[i]);
        atomicAdd(&sc[cm], 1);
    }
    __syncthreads();
    if (tid == 0) {
        float a = 0.f, b = 0.f;
        for (int cm = 0; cm < CC; ++cm) {
            if (sc[cm] > 0) {
                a += si[cm] / (float)sc[cm];
                b += se[cm] / (float)sc[cm];
            }
        }
        out[0] = a;
        out[1] = 0.5f * b;
    }
}

// ---------------------------------------------------------------------------
extern "C" void kernel_launch(void* const* d_in, const int* in_sizes, int n_in,
                              void* d_out, int out_size, void* d_ws, size_t ws_size,
                              hipStream_t stream) {
    const float* feats   = (const float*)d_in[0];
    const int*   indexes = (const int*)d_in[1];
    const int*   ltab    = (const int*)d_in[2];
    const int*   ctab    = (const int*)d_in[3];
    const float* centers = (const float*)d_in[4];
    float* out = (float*)d_out;

    char* p = (char*)d_ws;
    float*  cand    = (float*)p;   p += (size_t)NS * CAP * sizeof(float);   // 2.10 MB
    float*  partial = (float*)p;   p += (size_t)NBLK * NS * sizeof(float);  // 4.10 MB
    float*  posbuf  = (float*)p;   p += (size_t)NS * CC * sizeof(float);    // 16 KB
    ushort* fb      = (ushort*)p;  p += (size_t)NS * DDIM * sizeof(ushort); // 256 KB
    int*    labels  = (int*)p;     p += 2048;
    int*    cams    = (int*)p;     p += 2048;
    float*  li      = (float*)p;   p += 2048;
    float*  le      = (float*)p;   p += 2048;
    int*    gcount  = (int*)p;     p += 2048;   // memset region start
    float*  sig_acc = (float*)p;   p += 64;

    // zero the atomic-append counters + sigma accumulator (one contiguous memset)
    hipMemsetAsync(gcount, 0, 2048 + 64, stream);

    hipLaunchKernelGGL(k_norm_gather, dim3(NS), dim3(64), 0, stream,
                       feats, indexes, ltab, ctab, fb, labels, cams);
    hipLaunchKernelGGL(k_sigma, dim3(64), dim3(256), 0, stream,
                       fb, centers, sig_acc);
    hipLaunchKernelGGL(k_gemm_fused, dim3(NBLK), dim3(256), 0, stream,
                       fb, centers, labels, cams, sig_acc,
                       partial, cand, gcount, posbuf);
    hipLaunchKernelGGL(k_fixup, dim3(NS), dim3(256), 0, stream,
                       fb, centers, labels, cand, gcount);
    hipLaunchKernelGGL(k_row, dim3(NS), dim3(256), 0, stream,
                       partial, cand, gcount, posbuf, labels, cams, li, le);
    hipLaunchKernelGGL(k_finalize, dim3(1), dim3(256), 0, stream, li, le, cams, out);
}

// Round 10
// 218.335 us; speedup vs baseline: 1.1374x; 1.0787x over previous
//
#include <hip/hip_runtime.h>
#include <stdint.h>

#define NS   512      // batch size
#define DDIM 256      // feature dim
#define LL   8000     // labels
#define CC   8        // cameras
#define PP   64000    // proxies = LL*CC
#define KTOP 50
#define CAP  1024     // candidate buffer capacity per row
#define BC   64       // cols per block
#define NBLK (PP/BC)  // 1000 blocks
#define K2C  28.853900817779268f   // log2(e)/T, T=0.05

typedef float f32x4 __attribute__((ext_vector_type(4)));
typedef short bf16x8 __attribute__((ext_vector_type(8)));

__device__ __forceinline__ ushort f2bf(float x) {
    uint32_t b = __float_as_uint(x);
    b += 0x7fffu + ((b >> 16) & 1u);   // round-to-nearest-even
    return (ushort)(b >> 16);
}
__device__ __forceinline__ float bf2f(ushort u) {
    return __uint_as_float(((uint32_t)u) << 16);
}

// ---------------------------------------------------------------------------
// Kernel 1: normalize feats rows -> bf16; gather labels/cams; zero gcount.
__global__ void k_norm_gather(const float* __restrict__ feats,
                              const int* __restrict__ indexes,
                              const int* __restrict__ ltab,
                              const int* __restrict__ ctab,
                              ushort* __restrict__ feats_b,
                              int* __restrict__ labels,
                              int* __restrict__ cams,
                              int* __restrict__ gcount) {
    const int n = blockIdx.x;
    const int lane = threadIdx.x;  // 0..63
    f32x4 v = ((const f32x4*)(feats + (size_t)n * DDIM))[lane];
    float ss = v[0]*v[0] + v[1]*v[1] + v[2]*v[2] + v[3]*v[3];
#pragma unroll
    for (int off = 32; off > 0; off >>= 1) ss += __shfl_down(ss, off);
    float tot = __shfl(ss, 0);
    float sc = 1.0f / sqrtf(tot);
    ushort4 o;
    o.x = f2bf(v[0] * sc); o.y = f2bf(v[1] * sc);
    o.z = f2bf(v[2] * sc); o.w = f2bf(v[3] * sc);
    ((ushort4*)(feats_b + (size_t)n * DDIM))[lane] = o;
    if (lane == 0) {
        int idx = indexes[n];
        labels[n] = ltab[idx];
        cams[n] = ctab[idx];
        gcount[n] = 0;
    }
}

// ---------------------------------------------------------------------------
// Kernel 2: fused GEMM + loss-statistics epilogue. No sims materialization.
// Block b: 512 rows x 64 cols [b*64, b*64+64) (8 label groups).
// B staged in LDS bf16 (converted from f32 in-flight); A (L2-resident, bf16)
// loaded with one-kb-ahead register prefetch; per-block sigma estimated from
// own accumulators (outlier-clipped) -> tau; epilogue emits intra partials,
// positives, candidate appends.
__global__ __launch_bounds__(256, 2)
void k_gemm_fused(const ushort* __restrict__ A, const float* __restrict__ B,
                  const int* __restrict__ labels, const int* __restrict__ cams,
                  float* __restrict__ partial, float* __restrict__ cand,
                  int* __restrict__ gcount, float* __restrict__ posbuf) {
    const int bx    = blockIdx.x;          // 0..999
    const int cBase = bx * BC;
    const int gBase = cBase >> 3;          // first label group in block
    const int tid   = threadIdx.x;
    const int lane  = tid & 63;
    const int w     = tid >> 6;            // wave: rows [w*128, w*128+128)
    const int lr    = lane & 15;
    const int lk    = lane >> 4;

    __shared__ ushort sB[BC][264];         // [col][k], pad 256->264
    __shared__ int    s_lab[NS];
    __shared__ int    s_cam[NS];
    __shared__ float  s_intra[NS];
    __shared__ float  s_redA[256];
    __shared__ float  s_redB[256];
    __shared__ float  s_tau;

    // ---- stage B panel: 64 cols x 256 k, f32 -> bf16 (coalesced) ----
#pragma unroll
    for (int it = 0; it < 16; ++it) {
        int q   = tid + it * 256;          // f32x4 chunk id, 0..4095
        int col = q >> 6;                  // 0..63
        int k4  = q & 63;                  // f32x4 within col
        f32x4 a = *(const f32x4*)(B + (size_t)(cBase + col) * DDIM + k4 * 4);
        ushort4 o;
        o.x = f2bf(a[0]); o.y = f2bf(a[1]); o.z = f2bf(a[2]); o.w = f2bf(a[3]);
        *(ushort4*)(&sB[col][k4 * 4]) = o;
    }
    for (int r = tid; r < NS; r += 256) {
        s_lab[r] = labels[r];
        s_cam[r] = cams[r];
        s_intra[r] = 0.0f;
    }
    __syncthreads();

    // ---- MFMA main loop with one-kb-ahead A prefetch ----
    const ushort* Abase = A + (size_t)(w * 128) * DDIM;
    bf16x8 acur[8];
#pragma unroll
    for (int m = 0; m < 8; ++m)
        acur[m] = *(const bf16x8*)(Abase + (size_t)(m * 16 + lr) * DDIM + lk * 8);

    f32x4 zero = {0.f, 0.f, 0.f, 0.f};
    f32x4 acc[8][4];
#pragma unroll
    for (int m = 0; m < 8; ++m)
#pragma unroll
        for (int nn = 0; nn < 4; ++nn) acc[m][nn] = zero;

#pragma unroll
    for (int kb = 0; kb < 8; ++kb) {
        const int kpos = kb * 32 + lk * 8;
        bf16x8 bfr[4];
#pragma unroll
        for (int nn = 0; nn < 4; ++nn)
            bfr[nn] = *(const bf16x8*)(&sB[nn * 16 + lr][kpos]);
        bf16x8 anxt[8];
        if (kb < 7) {
#pragma unroll
            for (int m = 0; m < 8; ++m)
                anxt[m] = *(const bf16x8*)(Abase + (size_t)(m * 16 + lr) * DDIM + kpos + 32);
        }
#pragma unroll
        for (int m = 0; m < 8; ++m)
#pragma unroll
            for (int nn = 0; nn < 4; ++nn)
                acc[m][nn] = __builtin_amdgcn_mfma_f32_16x16x32_bf16(acur[m], bfr[nn], acc[m][nn], 0, 0, 0);
        if (kb < 7) {
#pragma unroll
            for (int m = 0; m < 8; ++m) acur[m] = anxt[m];
        }
    }

    // ---- per-block sigma from own accumulators (clip |v|<0.25 vs sigma~1/16) ----
    float ss = 0.0f, sc2 = 0.0f;
#pragma unroll
    for (int m = 0; m < 8; ++m)
#pragma unroll
        for (int nn = 0; nn < 4; ++nn)
#pragma unroll
            for (int j = 0; j < 4; ++j) {
                float v = acc[m][nn][j];
                if (fabsf(v) < 0.25f) { ss += v * v; sc2 += 1.0f; }
            }
    s_redA[tid] = ss; s_redB[tid] = sc2;
    __syncthreads();
    for (int off = 128; off > 0; off >>= 1) {
        if (tid < off) { s_redA[tid] += s_redA[tid + off]; s_redB[tid] += s_redB[tid + off]; }
        __syncthreads();
    }
    if (tid == 0) s_tau = 2.9f * sqrtf(s_redA[0] / fmaxf(s_redB[0], 1.0f));
    __syncthreads();
    const float tau = s_tau;

    // ---- epilogue: C/D layout col = lane&15 (+16nn), row = lk*4 + j (+16m) ----
#pragma unroll
    for (int m = 0; m < 8; ++m) {
#pragma unroll
        for (int j = 0; j < 4; ++j) {
            const int r   = w * 128 + m * 16 + lk * 4 + j;
            const int lab = s_lab[r];
            const int cm  = s_cam[r];
            const bool mycam  = ((lr & 7) == cm);
            const bool hasLab = ((unsigned)(lab - gBase) < 8u);
            float isum = 0.0f;
#pragma unroll
            for (int nn = 0; nn < 4; ++nn) {
                const float v = acc[m][nn][j];
                if (mycam) isum += exp2f(v * K2C);
                const int g = gBase + ((nn * 16 + lr) >> 3);
                if (hasLab && g == lab) {
                    posbuf[r * CC + (lr & 7)] = v;
                } else if (v > tau) {
                    int id = atomicAdd(&gcount[r], 1);
                    if (id < CAP) cand[(size_t)r * CAP + id] = v;
                }
            }
            if (mycam) atomicAdd(&s_intra[r], isum);
        }
    }
    __syncthreads();
    for (int r = tid; r < NS; r += 256)
        partial[(size_t)bx * NS + r] = s_intra[r];
}

// ---------------------------------------------------------------------------
// Kernel 3: per-row losses, with merged fixup backstop (block-uniform path).
__global__ __launch_bounds__(256)
void k_row(const ushort* __restrict__ fb, const float* __restrict__ B,
           const float* __restrict__ partial, const float* __restrict__ cand,
           const int* __restrict__ gcount, const float* __restrict__ posbuf,
           const int* __restrict__ labels, const int* __restrict__ cams,
           float* __restrict__ li, float* __restrict__ le) {
    const int n = blockIdx.x;
    const int tid = threadIdx.x;
    __shared__ float red[256];
    __shared__ int   redi[256];
    __shared__ float spos[CC];
    __shared__ float scand[CAP];
    __shared__ float f[DDIM];
    __shared__ float s_lo, s_hi;
    __shared__ int   s_done, s_cnt;

    // ---- intra: sum NBLK partials ----
    float s = 0.0f;
    for (int b = tid; b < NBLK; b += 256) s += partial[(size_t)b * NS + n];
    red[tid] = s;
    __syncthreads();
    for (int off = 128; off > 0; off >>= 1) {
        if (tid < off) red[tid] += red[tid + off];
        __syncthreads();
    }
    if (tid < CC) spos[tid] = posbuf[n * CC + tid];
    __syncthreads();
    if (tid == 0) li[n] = logf(red[0]) - 20.0f * spos[cams[n]];

    // ---- candidates: fast path or bisection fixup (block-uniform) ----
    int c = gcount[n];
    if (c >= KTOP && c <= CAP) {
        for (int i = tid; i < c; i += 256) scand[i] = cand[(size_t)n * CAP + i];
    } else {
        if (tid < DDIM) f[tid] = bf2f(fb[(size_t)n * DDIM + tid]);
        const int label = labels[n];
        if (tid == 0) { s_lo = -1.01f; s_hi = 1.01f; s_done = 0; s_cnt = 0; }
        __syncthreads();
        for (int it = 0; it < 16; ++it) {
            if (s_done) break;                     // uniform: settled by barrier
            float tm = 0.5f * (s_lo + s_hi);
            int cnt = 0;
            for (int p = tid; p < PP; p += 256) {
                if ((p >> 3) == label) continue;
                const float* col = B + (size_t)p * DDIM;
                float d = 0.0f;
                for (int k = 0; k < DDIM; ++k) d += f[k] * bf2f(f2bf(col[k]));
                cnt += (d > tm);
            }
            redi[tid] = cnt;
            __syncthreads();
            for (int off = 128; off > 0; off >>= 1) {
                if (tid < off) redi[tid] += redi[tid + off];
                __syncthreads();
            }
            int tot = redi[0];
            __syncthreads();
            if (tot >= KTOP && tot <= CAP) {
                if (tid == 0) s_cnt = 0;
                __syncthreads();
                for (int p = tid; p < PP; p += 256) {
                    if ((p >> 3) == label) continue;
                    const float* col = B + (size_t)p * DDIM;
                    float d = 0.0f;
                    for (int k = 0; k < DDIM; ++k) d += f[k] * bf2f(f2bf(col[k]));
                    if (d > tm) {
                        int id = atomicAdd(&s_cnt, 1);
                        if (id < CAP) scand[id] = d;
                    }
                }
                __syncthreads();
                if (tid == 0) s_done = 1;
            } else {
                if (tid == 0) { if (tot < KTOP) s_hi = tm; else s_lo = tm; }
            }
            __syncthreads();
        }
        if (!s_done) {   // last resort: collect at s_lo, truncate at CAP
            if (tid == 0) s_cnt = 0;
            __syncthreads();
            float tl = s_lo;
            for (int p = tid; p < PP; p += 256) {
                if ((p >> 3) == label) continue;
                const float* col = B + (size_t)p * DDIM;
                float d = 0.0f;
                for (int k = 0; k < DDIM; ++k) d += f[k] * bf2f(f2bf(col[k]));
                if (d > tl) {
                    int id = atomicAdd(&s_cnt, 1);
                    if (id < CAP) scand[id] = d;
                }
            }
        }
        __syncthreads();
        c = s_cnt;
        if (c > CAP) c = CAP;
    }
    __syncthreads();

    // ---- inter: exact top-K by rank counting + positives ----
    float sum = 0.0f;
    for (int i = tid; i < c; i += 256) {
        float v = scand[i];
        int rk = 0;
        for (int j = 0; j < c; ++j) {
            float u = scand[j];
            rk += (u > v) || (u == v && j < i);
        }
        if (rk < KTOP) sum += exp2f(v * K2C);
    }
    if (tid < CC) sum += exp2f(spos[tid] * K2C);
    red[tid] = sum;
    __syncthreads();
    for (int off = 128; off > 0; off >>= 1) {
        if (tid < off) red[tid] += red[tid + off];
        __syncthreads();
    }
    if (tid == 0) {
        float ps = 0.0f;
#pragma unroll
        for (int j = 0; j < CC; ++j) ps += spos[j];
        le[n] = logf(red[0]) - 2.5f * ps;   // 20/8 = 2.5
    }
}

// ---------------------------------------------------------------------------
// Kernel 4: per-camera segment means -> 2 outputs.
__global__ void k_finalize(const float* __restrict__ li, const float* __restrict__ le,
                           const int* __restrict__ cams, float* __restrict__ out) {
    __shared__ float si[CC], se[CC];
    __shared__ int sc[CC];
    int tid = threadIdx.x;
    if (tid < CC) { si[tid] = 0.f; se[tid] = 0.f; sc[tid] = 0; }
    __syncthreads();
    for (int i = tid; i < NS; i += 256) {
        int cm = cams[i];
        atomicAdd(&si[cm], li[i]);
        atomicAdd(&se[cm], le[i]);
        atomicAdd(&sc[cm], 1);
    }
    __syncthreads();
    if (tid == 0) {
        float a = 0.f, b = 0.f;
        for (int cm = 0; cm < CC; ++cm) {
            if (sc[cm] > 0) {
                a += si[cm] / (float)sc[cm];
                b += se[cm] / (float)sc[cm];
            }
        }
        out[0] = a;
        out[1] = 0.5f * b;
    }
}

// ---------------------------------------------------------------------------
extern "C" void kernel_launch(void* const* d_in, const int* in_sizes, int n_in,
                              void* d_out, int out_size, void* d_ws, size_t ws_size,
                              hipStream_t stream) {
    const float* feats   = (const float*)d_in[0];
    const int*   indexes = (const int*)d_in[1];
    const int*   ltab    = (const int*)d_in[2];
    const int*   ctab    = (const int*)d_in[3];
    const float* centers = (const float*)d_in[4];
    float* out = (float*)d_out;

    char* p = (char*)d_ws;
    float*  cand    = (float*)p;   p += (size_t)NS * CAP * sizeof(float);   // 2.10 MB
    float*  partial = (float*)p;   p += (size_t)NBLK * NS * sizeof(float);  // 2.05 MB
    float*  posbuf  = (float*)p;   p += (size_t)NS * CC * sizeof(float);    // 16 KB
    ushort* fb      = (ushort*)p;  p += (size_t)NS * DDIM * sizeof(ushort); // 256 KB
    int*    labels  = (int*)p;     p += 2048;
    int*    cams    = (int*)p;     p += 2048;
    float*  li      = (float*)p;   p += 2048;
    float*  le      = (float*)p;   p += 2048;
    int*    gcount  = (int*)p;     p += 2048;

    hipLaunchKernelGGL(k_norm_gather, dim3(NS), dim3(64), 0, stream,
                       feats, indexes, ltab, ctab, fb, labels, cams, gcount);
    hipLaunchKernelGGL(k_gemm_fused, dim3(NBLK), dim3(256), 0, stream,
                       fb, centers, labels, cams, partial, cand, gcount, posbuf);
    hipLaunchKernelGGL(k_row, dim3(NS), dim3(256), 0, stream,
                       fb, centers, partial, cand, gcount, posbuf, labels, cams, li, le);
    hipLaunchKernelGGL(k_finalize, dim3(1), dim3(256), 0, stream, li, le, cams, out);
}